// Round 17
// baseline (825.616 us; speedup 1.0000x reference)
//
#include <hip/hip_runtime.h>

#define DEVI __device__ __forceinline__

typedef __attribute__((ext_vector_type(8))) __bf16 bf16x8;
typedef __attribute__((ext_vector_type(4))) float f32x4;
typedef unsigned short u16;
typedef unsigned int u32;

static constexpr int kB = 32;
static constexpr int kL = 3137;           // 56*56+1
static constexpr int kM = kB * kL;        // 100384 rows total
static constexpr int kHeads = 12;
static constexpr float kScale = 0.17677669529663687f;  // 32^-0.5
static constexpr int kLnBlocks = (kM + 3) / 4;         // 25096
static constexpr int kCvtBlocks = 6912;

DEVI u16 f2b(float f) {                   // f32 -> bf16 RNE
  u32 u = __float_as_uint(f);
  u32 r = (u + 0x7fffu + ((u >> 16) & 1u)) >> 16;
  return (u16)r;
}
DEVI float blo(u32 u) { return __uint_as_float(u << 16); }
DEVI float bhi(u32 u) { return __uint_as_float(u & 0xffff0000u); }
DEVI float b2f(u16 h) { return __uint_as_float(((u32)h) << 16); }

DEVI void async16(const void* g, void* l) {
  __builtin_amdgcn_global_load_lds((const __attribute__((address_space(1))) u32*)g,
                                   (__attribute__((address_space(3))) u32*)l, 16, 0, 0);
}

DEVI float wred_max(float v) {
#pragma unroll
  for (int o = 32; o; o >>= 1) v = fmaxf(v, __shfl_xor(v, o));
  return v;
}
DEVI float wred_sum(float v) {
#pragma unroll
  for (int o = 32; o; o >>= 1) v += __shfl_xor(v, o);
  return v;
}

// ---------------- fused prep: LN1 (f32->bf16) + weight cvt + bias table ----------------
__global__ __launch_bounds__(256)
void prep(const float* __restrict__ x, const float* __restrict__ gam,
          const float* __restrict__ bet, u16* __restrict__ lnout,
          const float* __restrict__ a, const float* __restrict__ b,
          const float* __restrict__ c2, const float* __restrict__ d,
          u16* __restrict__ oa, u16* __restrict__ ob,
          u16* __restrict__ oc, u16* __restrict__ od,
          const float* __restrict__ relb, float* __restrict__ bf) {
  int bid = blockIdx.x;
  if (bid < kLnBlocks) {
    int row = bid * 4 + (threadIdx.x >> 6);
    if (row >= kM) return;
    int lane = threadIdx.x & 63;
    const float2* xr = (const float2*)(x + (size_t)row * 384);
    float2 v[3];
    float s = 0.f, s2 = 0.f;
#pragma unroll
    for (int i = 0; i < 3; i++) {
      v[i] = xr[lane + 64 * i];
      s += v[i].x + v[i].y;
      s2 += v[i].x * v[i].x + v[i].y * v[i].y;
    }
    s = wred_sum(s);
    s2 = wred_sum(s2);
    float mean = s * (1.f / 384.f);
    float var = s2 * (1.f / 384.f) - mean * mean;
    float rinv = rsqrtf(var + 1e-5f);
    const float2* gp = (const float2*)gam;
    const float2* bp = (const float2*)bet;
    u32* orow = (u32*)(lnout + (size_t)row * 384);
#pragma unroll
    for (int i = 0; i < 3; i++) {
      int idx = lane + 64 * i;
      float2 gg = gp[idx], bb = bp[idx];
      float lo = (v[i].x - mean) * rinv * gg.x + bb.x;
      float hi = (v[i].y - mean) * rinv * gg.y + bb.y;
      orow[idx] = (u32)f2b(lo) | ((u32)f2b(hi) << 16);
    }
  } else if (bid < kLnBlocks + kCvtBlocks) {
    int i = (bid - kLnBlocks) * 256 + threadIdx.x;
    if (i < 442368) oa[i] = f2b(a[i]);
    else if (i < 589824) ob[i - 442368] = f2b(b[i - 442368]);
    else if (i < 1179648) oc[i - 589824] = f2b(c2[i - 589824]);
    else od[i - 1179648] = f2b(d[i - 1179648]);
  } else {
    int blk = bid - (kLnBlocks + kCvtBlocks);          // cls*12 + h
    int cls = blk / 12, h = blk % 12;
    int clsH = (cls >> 1) & 1, clsW = cls & 1;
    for (int idx = threadIdx.x; idx < 4096; idx += 256) {
      int k = idx >> 6, q = idx & 63;
      float v = 0.f;
      if (k >= 50) {
        v = -1e9f;
      } else if (k >= 1 && q < 49) {
        int kt = k - 1, ki = kt / 7, kj = kt % 7;
        int qi = q / 7, qj = q % 7;
        v = relb[((qi - ki + 6) * 13 + (qj - kj + 6)) * 12 + h];
        int rq = (clsH ? (qi < 4 ? 1 : 2) : 0) * 3 + (clsW ? (qj < 4 ? 1 : 2) : 0);
        int rk = (clsH ? (ki < 4 ? 1 : 2) : 0) * 3 + (clsW ? (kj < 4 ? 1 : 2) : 0);
        if (rq != rk) v -= 100.f;
      }
      bf[(size_t)blk * 4096 + idx] = v;
    }
  }
}

// ---------------- LayerNorm over 384 (bf16 in): 4 rows/block, u32 vec ----------------
__global__ __launch_bounds__(256)
void ln384b(const u16* __restrict__ x, const float* __restrict__ gam,
            const float* __restrict__ bet, u16* __restrict__ out, int rows) {
  int row = blockIdx.x * 4 + (threadIdx.x >> 6);
  if (row >= rows) return;
  int lane = threadIdx.x & 63;
  const u32* xr = (const u32*)(x + (size_t)row * 384);
  float vl[3], vh[3];
  float s = 0.f, s2 = 0.f;
#pragma unroll
  for (int i = 0; i < 3; i++) {
    u32 u = xr[lane + 64 * i];
    vl[i] = blo(u); vh[i] = bhi(u);
    s += vl[i] + vh[i];
    s2 += vl[i] * vl[i] + vh[i] * vh[i];
  }
  s = wred_sum(s);
  s2 = wred_sum(s2);
  float mean = s * (1.f / 384.f);
  float var = s2 * (1.f / 384.f) - mean * mean;
  float rinv = rsqrtf(var + 1e-5f);
  const float2* gp = (const float2*)gam;
  const float2* bp = (const float2*)bet;
  u32* orow = (u32*)(out + (size_t)row * 384);
#pragma unroll
  for (int i = 0; i < 3; i++) {
    int idx = lane + 64 * i;
    float2 gg = gp[idx], bb = bp[idx];
    float lo = (vl[i] - mean) * rinv * gg.x + bb.x;
    float hi = (vh[i] - mean) * rinv * gg.y + bb.y;
    orow[idx] = (u32)f2b(lo) | ((u32)f2b(hi) << 16);
  }
}

// tanh-form gelu; |err| <= ~1e-3, below bf16 quant noise after fc2.
DEVI float gelu_fast(float v) {
  float u2 = v * (1.5957691216f + 0.0713548162f * v * v);
  return v / (1.f + __expf(-u2));
}

// ---------------- bf16 MFMA GEMM (K-loop unrolled x3: static buffer rotation) ----------------
// 128x128 tile, BK=32, 3-buf LDS, counted vmcnt(4), proven zero-conflict swizzle
// pair, bijective XCD swizzle, setprio, LDS-transpose epilogues.
// NT (=K/32) is divisible by 3 for ALL uses (12,12,12,48) -> unroll by 3 makes
// every LDS buffer index compile-time constant (kills ~15-20 VALU addr ops/iter;
// VALUBusy 32% > MfmaUtil 27% said address math was on the critical path).
// EPI: 0 = bias -> bf16 ; 2 = bias + gelu_fast -> bf16 ;
//      3 = bias + res(f32) -> bf16 ; 4 = bias + res(bf16) -> f32
template <int EPI>
__global__ __launch_bounds__(256)
void gemm_bt(const u16* __restrict__ A, const u16* __restrict__ W,
             const float* __restrict__ bias, const void* __restrict__ resv,
             void* __restrict__ outp, int M, int N, int K, int NX) {
  // T1: bijective XCD swizzle (m204) on flattened 1D grid
  const int nwg = gridDim.x;
  const int orig = blockIdx.x;
  const int xcd = orig & 7, rest = orig >> 3;
  const int q8 = nwg >> 3, r8 = nwg & 7;
  const int id = ((xcd < r8) ? xcd * (q8 + 1) : r8 * (q8 + 1) + (xcd - r8) * q8) + rest;
  const int col0 = (id % NX) * 128, row0 = (id / NX) * 128;

  const int tid = threadIdx.x, lane = tid & 63, wv = tid >> 6;
  __shared__ __align__(16) u16 SMEM[24576];            // As: [0,12288) Bs: [12288,24576)
  const int wm = wv >> 1, wn = wv & 1;
  const int c = lane & 15, g = lane >> 4;
  const int NT = K >> 5;                               // divisible by 3 (12 or 48)

  f32x4 acc[4][4];
  f32x4 zero = {0.f, 0.f, 0.f, 0.f};
#pragma unroll
  for (int m = 0; m < 4; m++)
#pragma unroll
    for (int n = 0; n < 4; n++) acc[m][n] = zero;

  const int rr = lane >> 2;
  const int gnat = (lane & 3) ^ ((lane >> 3) & 3);     // proven source pre-swizzle

  const u16* baseA[2];
  const u16* baseB[2];
  u16* ldsA[2];
  u16* ldsB[2];
#pragma unroll
  for (int s = 0; s < 2; s++) {
    int ch = wv * 2 + s;
    int r = ch * 16 + rr;
    baseA[s] = A + (size_t)min(row0 + r, M - 1) * K + gnat * 8;
    baseB[s] = W + (size_t)min(col0 + r, N - 1) * K + gnat * 8;
    ldsA[s] = &SMEM[ch * 512];
    ldsB[s] = &SMEM[12288 + ch * 512];
  }

  float bv[4];
#pragma unroll
  for (int n = 0; n < 4; n++) bv[n] = bias[col0 + wn * 64 + n * 16 + c];

  // stage with compile-time buffer index
  auto stage = [&](int kt, int bfi) {
    int kk = kt * 32;
#pragma unroll
    for (int s = 0; s < 2; s++) {
      async16(baseA[s] + kk, ldsA[s] + bfi * 4096);
      async16(baseB[s] + kk, ldsB[s] + bfi * 4096);
    }
  };

  stage(0, 0);                                         // prologue: 8 in flight
  stage(1, 1);
  const int axor = ((g ^ ((c >> 1) & 3)) << 3);
  for (int kt = 0; kt < NT; kt += 3) {
#pragma unroll
    for (int u = 0; u < 3; u++) {                      // k = kt+u, buffer = u (static)
      int k = kt + u;
      if (k + 1 < NT) asm volatile("s_waitcnt vmcnt(4)" ::: "memory");
      else            asm volatile("s_waitcnt vmcnt(0)" ::: "memory");
      __builtin_amdgcn_s_barrier();
      if (k + 2 < NT) stage(k + 2, (u + 2) % 3);       // (k+2)%3 == (u+2)%3, static
      bf16x8 af[4], bw[4];
#pragma unroll
      for (int m = 0; m < 4; m++) {
        int row = wm * 64 + m * 16 + c;
        af[m] = *(const bf16x8*)&SMEM[u * 4096 + row * 32 + ((g ^ ((row >> 1) & 3)) << 3)];
      }
#pragma unroll
      for (int n = 0; n < 4; n++) {
        int row = wn * 64 + n * 16 + c;
        bw[n] = *(const bf16x8*)&SMEM[12288 + u * 4096 + row * 32 + ((g ^ ((row >> 1) & 3)) << 3)];
      }
      __builtin_amdgcn_s_setprio(1);
#pragma unroll
      for (int m = 0; m < 4; m++)
#pragma unroll
        for (int n = 0; n < 4; n++)
          acc[m][n] = __builtin_amdgcn_mfma_f32_16x16x32_bf16(af[m], bw[n], acc[m][n], 0, 0, 0);
      __builtin_amdgcn_s_setprio(0);
    }
  }
  (void)axor;

  __syncthreads();                                     // K-loop LDS fully retired
  if constexpr (EPI == 4) {
    // f32-out transpose epilogue, 2 half-passes of 32 rows; stride 68 f32
    float* T = (float*)SMEM + wv * 2176;
    const int l16 = lane & 15, rq4 = lane >> 4;
#pragma unroll
    for (int half = 0; half < 2; ++half) {
#pragma unroll
      for (int mm = 0; mm < 2; ++mm) {
        int m = half * 2 + mm;
#pragma unroll
        for (int j = 0; j < 4; j++) {
          int rl = mm * 16 + (g << 2) + j;
#pragma unroll
          for (int n = 0; n < 4; n++)
            T[rl * 68 + n * 16 + c] = acc[m][n][j] + bv[n];
        }
      }
#pragma unroll
      for (int it = 0; it < 8; ++it) {
        int rl = it * 4 + rq4;
        int rg = row0 + wm * 64 + half * 32 + rl;
        if (rg < M) {
          size_t off = (size_t)rg * N + col0 + wn * 64 + l16 * 4;
          float4 v4 = *(const float4*)&T[rl * 68 + l16 * 4];
          ushort4 r4 = *(const ushort4*)((const u16*)resv + off);
          v4.x += b2f(r4.x); v4.y += b2f(r4.y);
          v4.z += b2f(r4.z); v4.w += b2f(r4.w);
          *(float4*)((float*)outp + off) = v4;
        }
      }
    }
  } else {
    // bf16-out transpose epilogue: wave tile 64x64 u16, stride 72
    u16* T = SMEM + wv * 4608;
#pragma unroll
    for (int m = 0; m < 4; m++)
#pragma unroll
      for (int j = 0; j < 4; j++) {
        int rl = m * 16 + (g << 2) + j;
#pragma unroll
        for (int n = 0; n < 4; n++) {
          float vv = acc[m][n][j] + bv[n];
          u16 hv;
          if constexpr (EPI == 2) hv = f2b(gelu_fast(vv));
          else                    hv = f2b(vv);
          T[rl * 72 + n * 16 + c] = hv;
        }
      }
    __syncthreads();
    const int l8 = lane & 7, rq8 = lane >> 3;
    const int colB = col0 + wn * 64 + l8 * 8;
#pragma unroll
    for (int it = 0; it < 8; ++it) {
      int rl = it * 8 + rq8;
      int rg = row0 + wm * 64 + rl;
      if (rg < M) {
        uint4 q = *(const uint4*)&T[rl * 72 + l8 * 8];
        size_t off = (size_t)rg * N + colB;
        if constexpr (EPI == 3) {
          const float* rp = (const float*)resv + off;
          float4 ra = *(const float4*)rp;
          float4 rb2 = *(const float4*)(rp + 4);
          u32 w0 = (u32)f2b(b2f((u16)(q.x & 0xffff)) + ra.x) |
                   ((u32)f2b(b2f((u16)(q.x >> 16)) + ra.y) << 16);
          u32 w1 = (u32)f2b(b2f((u16)(q.y & 0xffff)) + ra.z) |
                   ((u32)f2b(b2f((u16)(q.y >> 16)) + ra.w) << 16);
          u32 w2 = (u32)f2b(b2f((u16)(q.z & 0xffff)) + rb2.x) |
                   ((u32)f2b(b2f((u16)(q.z >> 16)) + rb2.y) << 16);
          u32 w3 = (u32)f2b(b2f((u16)(q.w & 0xffff)) + rb2.z) |
                   ((u32)f2b(b2f((u16)(q.w >> 16)) + rb2.w) << 16);
          uint4 o4 = {w0, w1, w2, w3};
          *(uint4*)((u16*)outp + off) = o4;
        } else {
          *(uint4*)((u16*)outp + off) = q;
        }
      }
    }
  }
}

// ---------------- CLS attention reduce: LSE-merge 64 window partials ----------------
__global__ __launch_bounds__(64)
void cls_reduce64(const float* __restrict__ parts, u16* __restrict__ aout) {
  int bh = blockIdx.x;
  int b = bh / kHeads, h = bh % kHeads;
  int lane = threadIdx.x;
  __shared__ float sm[64];
  const float* base = parts + (size_t)bh * 64 * 34;
  float m = base[lane * 34];
  float e = base[lane * 34 + 1];
  sm[lane] = m;                                    // wave-internal, in-order
  float M = wred_max(m);
  float W = wred_sum(e * __expf(m - M));
  if (lane < 32) {
    float o = 0.f;
    for (int c2 = 0; c2 < 64; c2++)
      o += base[c2 * 34 + 2 + lane] * __expf(sm[c2] - M);
    aout[(size_t)b * kL * 384 + h * 32 + lane] = f2b(o / W);
  }
}

// ---------------- shifted-window attention + fused CLS partials ----------------
__global__ __launch_bounds__(256)
void win_attn2(const u16* __restrict__ qkv, const float* __restrict__ biasf,
               u16* __restrict__ aout, float* __restrict__ parts) {
  const int tid = threadIdx.x, lane = tid & 63, wv = tid >> 6;
  const int gid = blockIdx.x * 4 + wv;
  const int h = gid % 12;
  const int wr = gid / 12;        // 0..2047
  const int win = wr & 63, b = wr >> 6;
  const int wi = win >> 3, wj = win & 7;
  const int cls = ((wi == 7) ? 2 : 0) + ((wj == 7) ? 1 : 0);
  const int c = lane & 15, g = lane >> 4;

  __shared__ __align__(16) u16 KS[4][64 * 40];   // K row-major, row stride 40 u16 (80B)
  __shared__ __align__(16) u16 VT[4][32 * 72];   // V transposed [d][tok], stride 72 u16
  __shared__ int RW[4][52];
  __shared__ float FP[4][52];                    // time-shared: q_cls (0..31) then p (0..49)
  u16* Ks = KS[wv];
  u16* Vt = VT[wv];
  int* Rows = RW[wv];
  float* Fp = FP[wv];

#pragma unroll
  for (int it = 0; it < 2; ++it) {
    int idx = it * 64 + lane;
    int tok = idx >> 1, half = idx & 1;
    if (tok < 50) {
      int row;
      if (tok == 0) {
        row = b * kL;                                  // CLS
      } else {
        int n = tok - 1;
        int i = n / 7, j = n % 7;
        int r = wi * 7 + i, c2 = wj * 7 + j;           // rolled-canvas coords
        int orr = r + 3; if (orr >= 56) orr -= 56;     // original coords
        int occ = c2 + 3; if (occ >= 56) occ -= 56;
        row = b * kL + 1 + orr * 56 + occ;
      }
      if (half == 0) Rows[tok] = row;
      const u16* base = qkv + (size_t)row * 1152 + h * 32 + half * 16;
      uint4 k0 = *(const uint4*)(base + 384);
      uint4 k1 = *(const uint4*)(base + 384 + 8);
      *(uint4*)&Ks[tok * 40 + half * 16] = k0;
      *(uint4*)&Ks[tok * 40 + half * 16 + 8] = k1;
      uint4 v0 = *(const uint4*)(base + 768);
      uint4 v1 = *(const uint4*)(base + 768 + 8);
      u32 vw[8] = {v0.x, v0.y, v0.z, v0.w, v1.x, v1.y, v1.z, v1.w};
#pragma unroll
      for (int m = 0; m < 8; ++m) {
        Vt[(half * 16 + m * 2 + 0) * 72 + tok] = (u16)(vw[m] & 0xffffu);
        Vt[(half * 16 + m * 2 + 1) * 72 + tok] = (u16)(vw[m] >> 16);
      }
    } else {
      uint4 z = {0u, 0u, 0u, 0u};
      *(uint4*)&Ks[tok * 40 + half * 16] = z;
      *(uint4*)&Ks[tok * 40 + half * 16 + 8] = z;
#pragma unroll
      for (int m = 0; m < 16; ++m) Vt[(half * 16 + m) * 72 + tok] = 0;
    }
  }
  __syncthreads();

  // ---- fused CLS-query partial over this window's keys (all from LDS) ----
  {
    if (lane < 32)
      Fp[lane] = b2f(qkv[(size_t)(b * kL) * 1152 + h * 32 + lane]) * kScale;
    float sc = -1e30f;
    if (lane <= 49 && (lane >= 1 || win == 0)) {       // CLS self-key only in window 0
      sc = 0.f;
      const u16* kr = &Ks[lane * 40];
#pragma unroll
      for (int d4 = 0; d4 < 4; d4++) {
        uint4 u = *(const uint4*)(kr + d4 * 8);
        sc += Fp[d4*8+0]*blo(u.x) + Fp[d4*8+1]*bhi(u.x)
            + Fp[d4*8+2]*blo(u.y) + Fp[d4*8+3]*bhi(u.y)
            + Fp[d4*8+4]*blo(u.z) + Fp[d4*8+5]*bhi(u.z)
            + Fp[d4*8+6]*blo(u.w) + Fp[d4*8+7]*bhi(u.w);
      }
    }
    float mloc = wred_max(sc);
    float pcls = (sc > -1e29f) ? __expf(sc - mloc) : 0.f;
    float esum = wred_sum(pcls);
    if (lane < 50) Fp[lane] = pcls;                    // overwrite q (done with it)
    float* pp = parts + (size_t)((b * 12 + h) * 64 + win) * 34;
    if (lane == 0) { pp[0] = mloc; pp[1] = esum; }
    if (lane < 32) {
      float o = 0.f;
      for (int t = 0; t < 50; t++)
        o += Fp[t] * b2f(Vt[lane * 72 + t]);
      pp[2 + lane] = o;
    }
  }

  bf16x8 qf[4];
#pragma unroll
  for (int nt = 0; nt < 4; ++nt) {
    int q = nt * 16 + c;
    if (q > 48) q = 48;
    const u16* qp = qkv + (size_t)Rows[q + 1] * 1152 + h * 32 + g * 8;
    qf[nt] = *(const bf16x8*)qp;
  }

  f32x4 s[4][4];
  {
    f32x4 z = {0.f, 0.f, 0.f, 0.f};
    bf16x8 kf[4];
#pragma unroll
    for (int mt = 0; mt < 4; ++mt)
      kf[mt] = *(const bf16x8*)&Ks[(mt * 16 + c) * 40 + g * 8];
#pragma unroll
    for (int mt = 0; mt < 4; ++mt)
#pragma unroll
      for (int nt = 0; nt < 4; ++nt)
        s[mt][nt] = __builtin_amdgcn_mfma_f32_16x16x32_bf16(kf[mt], qf[nt], z, 0, 0, 0);
  }

  const float* bp = biasf + (size_t)(cls * 12 + h) * 4096;
  u32 wq[4][8];
#pragma unroll
  for (int nt = 0; nt < 4; ++nt) {
    float pv[16];
#pragma unroll
    for (int mt = 0; mt < 4; ++mt)
#pragma unroll
      for (int r = 0; r < 4; ++r)
        pv[mt * 4 + r] = s[mt][nt][r] * kScale + bp[(mt * 16 + g * 4 + r) * 64 + nt * 16 + c];
    float mx = pv[0];
#pragma unroll
    for (int i2 = 1; i2 < 16; ++i2) mx = fmaxf(mx, pv[i2]);
    mx = fmaxf(mx, __shfl_xor(mx, 16));
    mx = fmaxf(mx, __shfl_xor(mx, 32));
    float sum = 0.f;
#pragma unroll
    for (int i2 = 0; i2 < 16; ++i2) { pv[i2] = __expf(pv[i2] - mx); sum += pv[i2]; }
    sum += __shfl_xor(sum, 16);
    sum += __shfl_xor(sum, 32);
    float rs = 1.f / sum;
#pragma unroll
    for (int i2 = 0; i2 < 16; ++i2) pv[i2] *= rs;
#pragma unroll
    for (int mt = 0; mt < 4; ++mt) {
      u32 w0, w1;
      asm("v_cvt_pk_bf16_f32 %0, %1, %2" : "=v"(w0) : "v"(pv[mt * 4 + 0]), "v"(pv[mt * 4 + 1]));
      asm("v_cvt_pk_bf16_f32 %0, %1, %2" : "=v"(w1) : "v"(pv[mt * 4 + 2]), "v"(pv[mt * 4 + 3]));
      wq[nt][mt * 2 + 0] = w0;
      wq[nt][mt * 2 + 1] = w1;
    }
  }

  bf16x8 pa[4][2];
#pragma unroll
  for (int mt2 = 0; mt2 < 4; ++mt2)
#pragma unroll
    for (int ks = 0; ks < 2; ++ks) {
      union { u32 u[4]; bf16x8 v; } cvt;
#pragma unroll
      for (int wj2 = 0; wj2 < 4; ++wj2) {
        int srcLane = c + 16 * (((g & 1) << 1) + (wj2 >> 1));
        u32 a0 = (u32)__shfl((int)wq[mt2][(2 * ks + 0) * 2 + (wj2 & 1)], srcLane);
        u32 a1 = (u32)__shfl((int)wq[mt2][(2 * ks + 1) * 2 + (wj2 & 1)], srcLane);
        cvt.u[wj2] = (g < 2) ? a0 : a1;
      }
      pa[mt2][ks] = cvt.v;
    }

  f32x4 o[4][2];
  f32x4 z2 = {0.f, 0.f, 0.f, 0.f};
#pragma unroll
  for (int mt2 = 0; mt2 < 4; ++mt2)
#pragma unroll
    for (int ntd = 0; ntd < 2; ++ntd) o[mt2][ntd] = z2;
#pragma unroll
  for (int ks = 0; ks < 2; ++ks) {
    bf16x8 vf[2];
#pragma unroll
    for (int ntd = 0; ntd < 2; ++ntd)
      vf[ntd] = *(const bf16x8*)&Vt[(ntd * 16 + c) * 72 + ks * 32 + g * 8];
#pragma unroll
    for (int mt2 = 0; mt2 < 4; ++mt2)
#pragma unroll
      for (int ntd = 0; ntd < 2; ++ntd)
        o[mt2][ntd] = __builtin_amdgcn_mfma_f32_16x16x32_bf16(pa[mt2][ks], vf[ntd], o[mt2][ntd], 0, 0, 0);
  }

#pragma unroll
  for (int mt2 = 0; mt2 < 4; ++mt2)
#pragma unroll
    for (int r = 0; r < 4; ++r) {
      int q = mt2 * 16 + g * 4 + r;
      if (q < 49) {
        int row = Rows[q + 1];
        u16* op = aout + (size_t)row * 384 + h * 32 + c;
        op[0]  = f2b(o[mt2][0][r]);
        op[16] = f2b(o[mt2][1][r]);
      }
    }
}

// ---------------- launcher ----------------
extern "C" void kernel_launch(void* const* d_in, const int* in_sizes, int n_in,
                              void* d_out, int out_size, void* d_ws, size_t ws_size,
                              hipStream_t stream) {
  const float* x      = (const float*)d_in[0];
  const float* n1g    = (const float*)d_in[1];
  const float* n1b    = (const float*)d_in[2];
  const float* qkv_w  = (const float*)d_in[3];
  const float* qkv_b  = (const float*)d_in[4];
  const float* relb   = (const float*)d_in[5];
  const float* proj_w = (const float*)d_in[6];
  const float* proj_b = (const float*)d_in[7];
  const float* n2g    = (const float*)d_in[8];
  const float* n2b    = (const float*)d_in[9];
  const float* fc1_w  = (const float*)d_in[10];
  const float* fc1_b  = (const float*)d_in[11];
  const float* fc2_w  = (const float*)d_in[12];
  const float* fc2_b  = (const float*)d_in[13];
  float* out = (float*)d_out;
  char* ws = (char*)d_ws;

  // layout (max 312.7 MB): h2b now FULL-M (77MB) at 80.6MB; gb slid to 157.7MB.
  // Liveness: qkvb dead after win_attn2 -> x1b/h2b reuse its range; hbuf
  // (attn_out) dead after proj -> gb may overlap its range (written by fc1 later).
  u16* wqkv  = (u16*)(ws + 0);                       //  884,736 B
  u16* wproj = (u16*)(ws + 884736);                  //  294,912 B
  u16* wfc1  = (u16*)(ws + 1179648);                 // 1,179,648 B
  u16* wfc2  = (u16*)(ws + 2359296);                 // 1,179,648 B
  u16* qkvb  = (u16*)(ws + 3538944);                 // 231,284,736 B (dead after attention)
  u16* x1b   = (u16*)(ws + 3538944);                 // 77,094,912 B bf16 x1
  u16* h2b   = (u16*)(ws + 80633856);                // 77,094,912 B (LN2 out, FULL M)
  u16* gb    = (u16*)(ws + 157728768);               // 154,189,824 B (fc1 chunk out)
  u16* hbuf  = (u16*)(ws + 234823680);               // 77,094,912 B (h, then attn_out)
  float* biasf = (float*)(ws + 311918592);           //  786,432 B (tail slot)
  float* parts = (float*)d_out;                      // CLS partials: d_out dead until fc2

  prep<<<kLnBlocks + kCvtBlocks + 48, 256, 0, stream>>>(
      x, n1g, n1b, hbuf, qkv_w, proj_w, fc1_w, fc2_w,
      wqkv, wproj, wfc1, wfc2, relb, biasf);
  gemm_bt<0><<<9 * 785, 256, 0, stream>>>(hbuf, wqkv, qkv_b, nullptr, qkvb, kM, 1152, 384, 9);
  win_attn2<<<kB * 64 * kHeads / 4, 256, 0, stream>>>(qkvb, biasf, hbuf, parts);
  cls_reduce64<<<kB * kHeads, 64, 0, stream>>>(parts, hbuf);
  gemm_bt<3><<<3 * 785, 256, 0, stream>>>(hbuf, wproj, proj_b, x, x1b, kM, 384, 384, 3);

  // LN2 over full M in one launch (both MLP chunks depend only on x1b)
  ln384b<<<(kM + 3) / 4, 256, 0, stream>>>(x1b, n2g, n2b, h2b, kM);
  for (int c = 0; c < 2; c++) {
    int r0 = c * 50192, nr = 50192;
    gemm_bt<2><<<12 * 393, 256, 0, stream>>>(h2b + (size_t)r0 * 384, wfc1, fc1_b, nullptr,
                                             gb, nr, 1536, 384, 12);
    gemm_bt<4><<<3 * 393, 256, 0, stream>>>(gb, wfc2, fc2_b, x1b + (size_t)r0 * 384,
                                            out + (size_t)r0 * 384, nr, 384, 1536, 3);
  }
}

// Round 18
// 807.848 us; speedup vs baseline: 1.0220x; 1.0220x over previous
//
#include <hip/hip_runtime.h>

#define DEVI __device__ __forceinline__

typedef __attribute__((ext_vector_type(8))) __bf16 bf16x8;
typedef __attribute__((ext_vector_type(4))) float f32x4;
typedef unsigned short u16;
typedef unsigned int u32;

static constexpr int kB = 32;
static constexpr int kL = 3137;           // 56*56+1
static constexpr int kM = kB * kL;        // 100384 rows total
static constexpr int kHeads = 12;
static constexpr float kScale = 0.17677669529663687f;  // 32^-0.5
static constexpr int kLnBlocks = (kM + 3) / 4;         // 25096
static constexpr int kCvtBlocks = 6912;

DEVI u16 f2b(float f) {                   // f32 -> bf16 RNE
  u32 u = __float_as_uint(f);
  u32 r = (u + 0x7fffu + ((u >> 16) & 1u)) >> 16;
  return (u16)r;
}
DEVI float blo(u32 u) { return __uint_as_float(u << 16); }
DEVI float bhi(u32 u) { return __uint_as_float(u & 0xffff0000u); }
DEVI float b2f(u16 h) { return __uint_as_float(((u32)h) << 16); }

DEVI void async16(const void* g, void* l) {
  __builtin_amdgcn_global_load_lds((const __attribute__((address_space(1))) u32*)g,
                                   (__attribute__((address_space(3))) u32*)l, 16, 0, 0);
}

DEVI float wred_max(float v) {
#pragma unroll
  for (int o = 32; o; o >>= 1) v = fmaxf(v, __shfl_xor(v, o));
  return v;
}
DEVI float wred_sum(float v) {
#pragma unroll
  for (int o = 32; o; o >>= 1) v += __shfl_xor(v, o);
  return v;
}

// ---------------- fused prep: LN1 (f32->bf16) + weight cvt + bias table ----------------
__global__ __launch_bounds__(256)
void prep(const float* __restrict__ x, const float* __restrict__ gam,
          const float* __restrict__ bet, u16* __restrict__ lnout,
          const float* __restrict__ a, const float* __restrict__ b,
          const float* __restrict__ c2, const float* __restrict__ d,
          u16* __restrict__ oa, u16* __restrict__ ob,
          u16* __restrict__ oc, u16* __restrict__ od,
          const float* __restrict__ relb, float* __restrict__ bf) {
  int bid = blockIdx.x;
  if (bid < kLnBlocks) {
    int row = bid * 4 + (threadIdx.x >> 6);
    if (row >= kM) return;
    int lane = threadIdx.x & 63;
    const float2* xr = (const float2*)(x + (size_t)row * 384);
    float2 v[3];
    float s = 0.f, s2 = 0.f;
#pragma unroll
    for (int i = 0; i < 3; i++) {
      v[i] = xr[lane + 64 * i];
      s += v[i].x + v[i].y;
      s2 += v[i].x * v[i].x + v[i].y * v[i].y;
    }
    s = wred_sum(s);
    s2 = wred_sum(s2);
    float mean = s * (1.f / 384.f);
    float var = s2 * (1.f / 384.f) - mean * mean;
    float rinv = rsqrtf(var + 1e-5f);
    const float2* gp = (const float2*)gam;
    const float2* bp = (const float2*)bet;
    u32* orow = (u32*)(lnout + (size_t)row * 384);
#pragma unroll
    for (int i = 0; i < 3; i++) {
      int idx = lane + 64 * i;
      float2 gg = gp[idx], bb = bp[idx];
      float lo = (v[i].x - mean) * rinv * gg.x + bb.x;
      float hi = (v[i].y - mean) * rinv * gg.y + bb.y;
      orow[idx] = (u32)f2b(lo) | ((u32)f2b(hi) << 16);
    }
  } else if (bid < kLnBlocks + kCvtBlocks) {
    int i = (bid - kLnBlocks) * 256 + threadIdx.x;
    if (i < 442368) oa[i] = f2b(a[i]);
    else if (i < 589824) ob[i - 442368] = f2b(b[i - 442368]);
    else if (i < 1179648) oc[i - 589824] = f2b(c2[i - 589824]);
    else od[i - 1179648] = f2b(d[i - 1179648]);
  } else {
    int blk = bid - (kLnBlocks + kCvtBlocks);          // cls*12 + h
    int cls = blk / 12, h = blk % 12;
    int clsH = (cls >> 1) & 1, clsW = cls & 1;
    for (int idx = threadIdx.x; idx < 4096; idx += 256) {
      int k = idx >> 6, q = idx & 63;
      float v = 0.f;
      if (k >= 50) {
        v = -1e9f;
      } else if (k >= 1 && q < 49) {
        int kt = k - 1, ki = kt / 7, kj = kt % 7;
        int qi = q / 7, qj = q % 7;
        v = relb[((qi - ki + 6) * 13 + (qj - kj + 6)) * 12 + h];
        int rq = (clsH ? (qi < 4 ? 1 : 2) : 0) * 3 + (clsW ? (qj < 4 ? 1 : 2) : 0);
        int rk = (clsH ? (ki < 4 ? 1 : 2) : 0) * 3 + (clsW ? (kj < 4 ? 1 : 2) : 0);
        if (rq != rk) v -= 100.f;
      }
      bf[(size_t)blk * 4096 + idx] = v;
    }
  }
}

// ---------------- LayerNorm over 384 (bf16 in): 4 rows/block, u32 vec ----------------
__global__ __launch_bounds__(256)
void ln384b(const u16* __restrict__ x, const float* __restrict__ gam,
            const float* __restrict__ bet, u16* __restrict__ out, int rows) {
  int row = blockIdx.x * 4 + (threadIdx.x >> 6);
  if (row >= rows) return;
  int lane = threadIdx.x & 63;
  const u32* xr = (const u32*)(x + (size_t)row * 384);
  float vl[3], vh[3];
  float s = 0.f, s2 = 0.f;
#pragma unroll
  for (int i = 0; i < 3; i++) {
    u32 u = xr[lane + 64 * i];
    vl[i] = blo(u); vh[i] = bhi(u);
    s += vl[i] + vh[i];
    s2 += vl[i] * vl[i] + vh[i] * vh[i];
  }
  s = wred_sum(s);
  s2 = wred_sum(s2);
  float mean = s * (1.f / 384.f);
  float var = s2 * (1.f / 384.f) - mean * mean;
  float rinv = rsqrtf(var + 1e-5f);
  const float2* gp = (const float2*)gam;
  const float2* bp = (const float2*)bet;
  u32* orow = (u32*)(out + (size_t)row * 384);
#pragma unroll
  for (int i = 0; i < 3; i++) {
    int idx = lane + 64 * i;
    float2 gg = gp[idx], bb = bp[idx];
    float lo = (vl[i] - mean) * rinv * gg.x + bb.x;
    float hi = (vh[i] - mean) * rinv * gg.y + bb.y;
    orow[idx] = (u32)f2b(lo) | ((u32)f2b(hi) << 16);
  }
}

// tanh-form gelu; |err| <= ~1e-3, below bf16 quant noise after fc2.
DEVI float gelu_fast(float v) {
  float u2 = v * (1.5957691216f + 0.0713548162f * v * v);
  return v / (1.f + __expf(-u2));
}

// ---------------- bf16 MFMA GEMM (R3/R4 K-loop + LDS-transpose epilogues) ----------------
// 128x128 tile, BK=32, 3-buf LDS, counted vmcnt(4), proven zero-conflict swizzle
// pair, bijective XCD swizzle, setprio. BANKED-BEST R16 configuration (dynamic
// buffer rotation; unroll-x3 variant measured SLOWER in R17 and was reverted).
// EPI: 0 = bias -> bf16 ; 2 = bias + gelu_fast -> bf16 ;
//      3 = bias + res(f32) -> bf16 ; 4 = bias + res(bf16) -> f32 (2 half-passes)
template <int EPI>
__global__ __launch_bounds__(256)
void gemm_bt(const u16* __restrict__ A, const u16* __restrict__ W,
             const float* __restrict__ bias, const void* __restrict__ resv,
             void* __restrict__ outp, int M, int N, int K, int NX) {
  // T1: bijective XCD swizzle (m204) on flattened 1D grid
  const int nwg = gridDim.x;
  const int orig = blockIdx.x;
  const int xcd = orig & 7, rest = orig >> 3;
  const int q8 = nwg >> 3, r8 = nwg & 7;
  const int id = ((xcd < r8) ? xcd * (q8 + 1) : r8 * (q8 + 1) + (xcd - r8) * q8) + rest;
  const int col0 = (id % NX) * 128, row0 = (id / NX) * 128;

  const int tid = threadIdx.x, lane = tid & 63, wv = tid >> 6;
  __shared__ __align__(16) u16 SMEM[24576];            // As: [0,12288) Bs: [12288,24576)
  const int wm = wv >> 1, wn = wv & 1;
  const int c = lane & 15, g = lane >> 4;
  const int NT = K >> 5;

  f32x4 acc[4][4];
  f32x4 zero = {0.f, 0.f, 0.f, 0.f};
#pragma unroll
  for (int m = 0; m < 4; m++)
#pragma unroll
    for (int n = 0; n < 4; n++) acc[m][n] = zero;

  const int rr = lane >> 2;
  const int gnat = (lane & 3) ^ ((lane >> 3) & 3);     // proven source pre-swizzle

  // Hoisted staging addresses (row clamp + row*K once; stage adds kt*32 only)
  const u16* baseA[2];
  const u16* baseB[2];
  u16* ldsA[2];
  u16* ldsB[2];
#pragma unroll
  for (int s = 0; s < 2; s++) {
    int ch = wv * 2 + s;
    int r = ch * 16 + rr;
    baseA[s] = A + (size_t)min(row0 + r, M - 1) * K + gnat * 8;
    baseB[s] = W + (size_t)min(col0 + r, N - 1) * K + gnat * 8;
    ldsA[s] = &SMEM[ch * 512];
    ldsB[s] = &SMEM[12288 + ch * 512];
  }

  auto stage = [&](int kt, int bfi) {
    int kk = kt * 32;
#pragma unroll
    for (int s = 0; s < 2; s++) {
      async16(baseA[s] + kk, ldsA[s] + bfi * 4096);
      async16(baseB[s] + kk, ldsB[s] + bfi * 4096);
    }
  };

  float bv[4];
#pragma unroll
  for (int n = 0; n < 4; n++) bv[n] = bias[col0 + wn * 64 + n * 16 + c];

  stage(0, 0);                                         // prologue: 8 in flight
  stage(1, 1);
  int cur = 0;
  for (int kt = 0; kt < NT; ++kt) {
    if (kt + 1 < NT) asm volatile("s_waitcnt vmcnt(4)" ::: "memory");
    else             asm volatile("s_waitcnt vmcnt(0)" ::: "memory");
    __builtin_amdgcn_s_barrier();                      // all waves' phase loads landed
    if (kt + 2 < NT) {
      int nb = cur + 2; if (nb >= 3) nb -= 3;
      stage(kt + 2, nb);
    }
    bf16x8 af[4], bw[4];
#pragma unroll
    for (int m = 0; m < 4; m++) {
      int row = wm * 64 + m * 16 + c;
      af[m] = *(const bf16x8*)&SMEM[cur * 4096 + row * 32 + ((g ^ ((row >> 1) & 3)) << 3)];
    }
#pragma unroll
    for (int n = 0; n < 4; n++) {
      int row = wn * 64 + n * 16 + c;
      bw[n] = *(const bf16x8*)&SMEM[12288 + cur * 4096 + row * 32 + ((g ^ ((row >> 1) & 3)) << 3)];
    }
    __builtin_amdgcn_s_setprio(1);
#pragma unroll
    for (int m = 0; m < 4; m++)
#pragma unroll
      for (int n = 0; n < 4; n++)
        acc[m][n] = __builtin_amdgcn_mfma_f32_16x16x32_bf16(af[m], bw[n], acc[m][n], 0, 0, 0);
    __builtin_amdgcn_s_setprio(0);
    cur = cur + 1; if (cur >= 3) cur -= 3;
  }

  __syncthreads();                                     // K-loop LDS fully retired
  if constexpr (EPI == 4) {
    // f32-out transpose epilogue, 2 half-passes of 32 rows; stride 68 f32 (16B rows)
    float* T = (float*)SMEM + wv * 2176;
    const int l16 = lane & 15, rq4 = lane >> 4;
#pragma unroll
    for (int half = 0; half < 2; ++half) {
#pragma unroll
      for (int mm = 0; mm < 2; ++mm) {
        int m = half * 2 + mm;
#pragma unroll
        for (int j = 0; j < 4; j++) {
          int rl = mm * 16 + (g << 2) + j;
#pragma unroll
          for (int n = 0; n < 4; n++)
            T[rl * 68 + n * 16 + c] = acc[m][n][j] + bv[n];
        }
      }
      // per-wave-private T: intra-wave DS ordering suffices (no barrier)
#pragma unroll
      for (int it = 0; it < 8; ++it) {
        int rl = it * 4 + rq4;
        int rg = row0 + wm * 64 + half * 32 + rl;
        if (rg < M) {
          size_t off = (size_t)rg * N + col0 + wn * 64 + l16 * 4;
          float4 v4 = *(const float4*)&T[rl * 68 + l16 * 4];
          ushort4 r4 = *(const ushort4*)((const u16*)resv + off);
          v4.x += b2f(r4.x); v4.y += b2f(r4.y);
          v4.z += b2f(r4.z); v4.w += b2f(r4.w);
          *(float4*)((float*)outp + off) = v4;
        }
      }
    }
  } else {
    // bf16-out transpose epilogue: wave tile 64x64 u16, stride 72 (144B rows)
    u16* T = SMEM + wv * 4608;
#pragma unroll
    for (int m = 0; m < 4; m++)
#pragma unroll
      for (int j = 0; j < 4; j++) {
        int rl = m * 16 + (g << 2) + j;
#pragma unroll
        for (int n = 0; n < 4; n++) {
          float vv = acc[m][n][j] + bv[n];
          u16 hv;
          if constexpr (EPI == 2) hv = f2b(gelu_fast(vv));
          else                    hv = f2b(vv);
          T[rl * 72 + n * 16 + c] = hv;
        }
      }
    __syncthreads();
    const int l8 = lane & 7, rq8 = lane >> 3;
    const int colB = col0 + wn * 64 + l8 * 8;          // 8 u16 = 16B/lane, 128B/8 lanes
#pragma unroll
    for (int it = 0; it < 8; ++it) {
      int rl = it * 8 + rq8;
      int rg = row0 + wm * 64 + rl;
      if (rg < M) {
        uint4 q = *(const uint4*)&T[rl * 72 + l8 * 8];
        size_t off = (size_t)rg * N + colB;
        if constexpr (EPI == 3) {
          const float* rp = (const float*)resv + off;
          float4 ra = *(const float4*)rp;
          float4 rb2 = *(const float4*)(rp + 4);
          u32 w0 = (u32)f2b(b2f((u16)(q.x & 0xffff)) + ra.x) |
                   ((u32)f2b(b2f((u16)(q.x >> 16)) + ra.y) << 16);
          u32 w1 = (u32)f2b(b2f((u16)(q.y & 0xffff)) + ra.z) |
                   ((u32)f2b(b2f((u16)(q.y >> 16)) + ra.w) << 16);
          u32 w2 = (u32)f2b(b2f((u16)(q.z & 0xffff)) + rb2.x) |
                   ((u32)f2b(b2f((u16)(q.z >> 16)) + rb2.y) << 16);
          u32 w3 = (u32)f2b(b2f((u16)(q.w & 0xffff)) + rb2.z) |
                   ((u32)f2b(b2f((u16)(q.w >> 16)) + rb2.w) << 16);
          uint4 o4 = {w0, w1, w2, w3};
          *(uint4*)((u16*)outp + off) = o4;
        } else {
          *(uint4*)((u16*)outp + off) = q;
        }
      }
    }
  }
}

// ---------------- CLS attention reduce: LSE-merge 64 window partials ----------------
__global__ __launch_bounds__(64)
void cls_reduce64(const float* __restrict__ parts, u16* __restrict__ aout) {
  int bh = blockIdx.x;
  int b = bh / kHeads, h = bh % kHeads;
  int lane = threadIdx.x;
  __shared__ float sm[64];
  const float* base = parts + (size_t)bh * 64 * 34;
  float m = base[lane * 34];
  float e = base[lane * 34 + 1];
  sm[lane] = m;                                    // wave-internal, in-order
  float M = wred_max(m);
  float W = wred_sum(e * __expf(m - M));
  if (lane < 32) {
    float o = 0.f;
    for (int c2 = 0; c2 < 64; c2++)
      o += base[c2 * 34 + 2 + lane] * __expf(sm[c2] - M);
    aout[(size_t)b * kL * 384 + h * 32 + lane] = f2b(o / W);
  }
}

// ---------------- shifted-window attention + fused CLS partials ----------------
__global__ __launch_bounds__(256)
void win_attn2(const u16* __restrict__ qkv, const float* __restrict__ biasf,
               u16* __restrict__ aout, float* __restrict__ parts) {
  const int tid = threadIdx.x, lane = tid & 63, wv = tid >> 6;
  const int gid = blockIdx.x * 4 + wv;
  const int h = gid % 12;
  const int wr = gid / 12;        // 0..2047
  const int win = wr & 63, b = wr >> 6;
  const int wi = win >> 3, wj = win & 7;
  const int cls = ((wi == 7) ? 2 : 0) + ((wj == 7) ? 1 : 0);
  const int c = lane & 15, g = lane >> 4;

  __shared__ __align__(16) u16 KS[4][64 * 40];   // K row-major, row stride 40 u16 (80B)
  __shared__ __align__(16) u16 VT[4][32 * 72];   // V transposed [d][tok], stride 72 u16
  __shared__ int RW[4][52];
  __shared__ float FP[4][52];                    // time-shared: q_cls (0..31) then p (0..49)
  u16* Ks = KS[wv];
  u16* Vt = VT[wv];
  int* Rows = RW[wv];
  float* Fp = FP[wv];

#pragma unroll
  for (int it = 0; it < 2; ++it) {
    int idx = it * 64 + lane;
    int tok = idx >> 1, half = idx & 1;
    if (tok < 50) {
      int row;
      if (tok == 0) {
        row = b * kL;                                  // CLS
      } else {
        int n = tok - 1;
        int i = n / 7, j = n % 7;
        int r = wi * 7 + i, c2 = wj * 7 + j;           // rolled-canvas coords
        int orr = r + 3; if (orr >= 56) orr -= 56;     // original coords
        int occ = c2 + 3; if (occ >= 56) occ -= 56;
        row = b * kL + 1 + orr * 56 + occ;
      }
      if (half == 0) Rows[tok] = row;
      const u16* base = qkv + (size_t)row * 1152 + h * 32 + half * 16;
      uint4 k0 = *(const uint4*)(base + 384);
      uint4 k1 = *(const uint4*)(base + 384 + 8);
      *(uint4*)&Ks[tok * 40 + half * 16] = k0;
      *(uint4*)&Ks[tok * 40 + half * 16 + 8] = k1;
      uint4 v0 = *(const uint4*)(base + 768);
      uint4 v1 = *(const uint4*)(base + 768 + 8);
      u32 vw[8] = {v0.x, v0.y, v0.z, v0.w, v1.x, v1.y, v1.z, v1.w};
#pragma unroll
      for (int m = 0; m < 8; ++m) {
        Vt[(half * 16 + m * 2 + 0) * 72 + tok] = (u16)(vw[m] & 0xffffu);
        Vt[(half * 16 + m * 2 + 1) * 72 + tok] = (u16)(vw[m] >> 16);
      }
    } else {
      uint4 z = {0u, 0u, 0u, 0u};
      *(uint4*)&Ks[tok * 40 + half * 16] = z;
      *(uint4*)&Ks[tok * 40 + half * 16 + 8] = z;
#pragma unroll
      for (int m = 0; m < 16; ++m) Vt[(half * 16 + m) * 72 + tok] = 0;
    }
  }
  __syncthreads();

  // ---- fused CLS-query partial over this window's keys (all from LDS) ----
  {
    if (lane < 32)
      Fp[lane] = b2f(qkv[(size_t)(b * kL) * 1152 + h * 32 + lane]) * kScale;
    float sc = -1e30f;
    if (lane <= 49 && (lane >= 1 || win == 0)) {       // CLS self-key only in window 0
      sc = 0.f;
      const u16* kr = &Ks[lane * 40];
#pragma unroll
      for (int d4 = 0; d4 < 4; d4++) {
        uint4 u = *(const uint4*)(kr + d4 * 8);
        sc += Fp[d4*8+0]*blo(u.x) + Fp[d4*8+1]*bhi(u.x)
            + Fp[d4*8+2]*blo(u.y) + Fp[d4*8+3]*bhi(u.y)
            + Fp[d4*8+4]*blo(u.z) + Fp[d4*8+5]*bhi(u.z)
            + Fp[d4*8+6]*blo(u.w) + Fp[d4*8+7]*bhi(u.w);
      }
    }
    float mloc = wred_max(sc);
    float pcls = (sc > -1e29f) ? __expf(sc - mloc) : 0.f;
    float esum = wred_sum(pcls);
    if (lane < 50) Fp[lane] = pcls;                    // overwrite q (done with it)
    float* pp = parts + (size_t)((b * 12 + h) * 64 + win) * 34;
    if (lane == 0) { pp[0] = mloc; pp[1] = esum; }
    if (lane < 32) {
      float o = 0.f;
      for (int t = 0; t < 50; t++)
        o += Fp[t] * b2f(Vt[lane * 72 + t]);
      pp[2 + lane] = o;
    }
  }

  bf16x8 qf[4];
#pragma unroll
  for (int nt = 0; nt < 4; ++nt) {
    int q = nt * 16 + c;
    if (q > 48) q = 48;
    const u16* qp = qkv + (size_t)Rows[q + 1] * 1152 + h * 32 + g * 8;
    qf[nt] = *(const bf16x8*)qp;
  }

  f32x4 s[4][4];
  {
    f32x4 z = {0.f, 0.f, 0.f, 0.f};
    bf16x8 kf[4];
#pragma unroll
    for (int mt = 0; mt < 4; ++mt)
      kf[mt] = *(const bf16x8*)&Ks[(mt * 16 + c) * 40 + g * 8];
#pragma unroll
    for (int mt = 0; mt < 4; ++mt)
#pragma unroll
      for (int nt = 0; nt < 4; ++nt)
        s[mt][nt] = __builtin_amdgcn_mfma_f32_16x16x32_bf16(kf[mt], qf[nt], z, 0, 0, 0);
  }

  const float* bp = biasf + (size_t)(cls * 12 + h) * 4096;
  u32 wq[4][8];
#pragma unroll
  for (int nt = 0; nt < 4; ++nt) {
    float pv[16];
#pragma unroll
    for (int mt = 0; mt < 4; ++mt)
#pragma unroll
      for (int r = 0; r < 4; ++r)
        pv[mt * 4 + r] = s[mt][nt][r] * kScale + bp[(mt * 16 + g * 4 + r) * 64 + nt * 16 + c];
    float mx = pv[0];
#pragma unroll
    for (int i2 = 1; i2 < 16; ++i2) mx = fmaxf(mx, pv[i2]);
    mx = fmaxf(mx, __shfl_xor(mx, 16));
    mx = fmaxf(mx, __shfl_xor(mx, 32));
    float sum = 0.f;
#pragma unroll
    for (int i2 = 0; i2 < 16; ++i2) { pv[i2] = __expf(pv[i2] - mx); sum += pv[i2]; }
    sum += __shfl_xor(sum, 16);
    sum += __shfl_xor(sum, 32);
    float rs = 1.f / sum;
#pragma unroll
    for (int i2 = 0; i2 < 16; ++i2) pv[i2] *= rs;
#pragma unroll
    for (int mt = 0; mt < 4; ++mt) {
      u32 w0, w1;
      asm("v_cvt_pk_bf16_f32 %0, %1, %2" : "=v"(w0) : "v"(pv[mt * 4 + 0]), "v"(pv[mt * 4 + 1]));
      asm("v_cvt_pk_bf16_f32 %0, %1, %2" : "=v"(w1) : "v"(pv[mt * 4 + 2]), "v"(pv[mt * 4 + 3]));
      wq[nt][mt * 2 + 0] = w0;
      wq[nt][mt * 2 + 1] = w1;
    }
  }

  bf16x8 pa[4][2];
#pragma unroll
  for (int mt2 = 0; mt2 < 4; ++mt2)
#pragma unroll
    for (int ks = 0; ks < 2; ++ks) {
      union { u32 u[4]; bf16x8 v; } cvt;
#pragma unroll
      for (int wj2 = 0; wj2 < 4; ++wj2) {
        int srcLane = c + 16 * (((g & 1) << 1) + (wj2 >> 1));
        u32 a0 = (u32)__shfl((int)wq[mt2][(2 * ks + 0) * 2 + (wj2 & 1)], srcLane);
        u32 a1 = (u32)__shfl((int)wq[mt2][(2 * ks + 1) * 2 + (wj2 & 1)], srcLane);
        cvt.u[wj2] = (g < 2) ? a0 : a1;
      }
      pa[mt2][ks] = cvt.v;
    }

  f32x4 o[4][2];
  f32x4 z2 = {0.f, 0.f, 0.f, 0.f};
#pragma unroll
  for (int mt2 = 0; mt2 < 4; ++mt2)
#pragma unroll
    for (int ntd = 0; ntd < 2; ++ntd) o[mt2][ntd] = z2;
#pragma unroll
  for (int ks = 0; ks < 2; ++ks) {
    bf16x8 vf[2];
#pragma unroll
    for (int ntd = 0; ntd < 2; ++ntd)
      vf[ntd] = *(const bf16x8*)&Vt[(ntd * 16 + c) * 72 + ks * 32 + g * 8];
#pragma unroll
    for (int mt2 = 0; mt2 < 4; ++mt2)
#pragma unroll
      for (int ntd = 0; ntd < 2; ++ntd)
        o[mt2][ntd] = __builtin_amdgcn_mfma_f32_16x16x32_bf16(pa[mt2][ks], vf[ntd], o[mt2][ntd], 0, 0, 0);
  }

#pragma unroll
  for (int mt2 = 0; mt2 < 4; ++mt2)
#pragma unroll
    for (int r = 0; r < 4; ++r) {
      int q = mt2 * 16 + g * 4 + r;
      if (q < 49) {
        int row = Rows[q + 1];
        u16* op = aout + (size_t)row * 384 + h * 32 + c;
        op[0]  = f2b(o[mt2][0][r]);
        op[16] = f2b(o[mt2][1][r]);
      }
    }
}

// ---------------- launcher ----------------
extern "C" void kernel_launch(void* const* d_in, const int* in_sizes, int n_in,
                              void* d_out, int out_size, void* d_ws, size_t ws_size,
                              hipStream_t stream) {
  const float* x      = (const float*)d_in[0];
  const float* n1g    = (const float*)d_in[1];
  const float* n1b    = (const float*)d_in[2];
  const float* qkv_w  = (const float*)d_in[3];
  const float* qkv_b  = (const float*)d_in[4];
  const float* relb   = (const float*)d_in[5];
  const float* proj_w = (const float*)d_in[6];
  const float* proj_b = (const float*)d_in[7];
  const float* n2g    = (const float*)d_in[8];
  const float* n2b    = (const float*)d_in[9];
  const float* fc1_w  = (const float*)d_in[10];
  const float* fc1_b  = (const float*)d_in[11];
  const float* fc2_w  = (const float*)d_in[12];
  const float* fc2_b  = (const float*)d_in[13];
  float* out = (float*)d_out;
  char* ws = (char*)d_ws;

  u16* wqkv  = (u16*)(ws + 0);                       //  884,736 B
  u16* wproj = (u16*)(ws + 884736);                  //  294,912 B
  u16* wfc1  = (u16*)(ws + 1179648);                 // 1,179,648 B
  u16* wfc2  = (u16*)(ws + 2359296);                 // 1,179,648 B
  u16* qkvb  = (u16*)(ws + 3538944);                 // 231,284,736 B (dead after attention)
  u16* x1b   = (u16*)(ws + 3538944);                 // 77,094,912 B bf16 x1 (reuses qkvb head)
  u16* h2b   = (u16*)(ws + 80633856);                // 38,547,456 B (LN2 chunk out)
  u16* gb    = (u16*)(ws + 119181312);               // 154,189,824 B (fc1 chunk out)
  u16* hbuf  = (u16*)(ws + 234823680);               // 77,094,912 B (h, then attn_out)
  float* biasf = (float*)(ws + 311918592);           //  786,432 B (tail slot)
  float* parts = (float*)d_out;                      // CLS partials: d_out dead until fc2

  // fused prep: LN1 + weight converts + bias table (one launch, all independent)
  prep<<<kLnBlocks + kCvtBlocks + 48, 256, 0, stream>>>(
      x, n1g, n1b, hbuf, qkv_w, proj_w, fc1_w, fc2_w,
      wqkv, wproj, wfc1, wfc2, relb, biasf);
  gemm_bt<0><<<9 * 785, 256, 0, stream>>>(hbuf, wqkv, qkv_b, nullptr, qkvb, kM, 1152, 384, 9);
  win_attn2<<<kB * 64 * kHeads / 4, 256, 0, stream>>>(qkvb, biasf, hbuf, parts);
  cls_reduce64<<<kB * kHeads, 64, 0, stream>>>(parts, hbuf);
  gemm_bt<3><<<3 * 785, 256, 0, stream>>>(hbuf, wproj, proj_b, x, x1b, kM, 384, 384, 3);

  for (int c = 0; c < 2; c++) {
    int r0 = c * 50192, nr = 50192;
    ln384b<<<(nr + 3) / 4, 256, 0, stream>>>(x1b + (size_t)r0 * 384, n2g, n2b, h2b, nr);
    gemm_bt<2><<<12 * 393, 256, 0, stream>>>(h2b + 0, wfc1, fc1_b, nullptr, gb, nr, 1536, 384, 12);
    gemm_bt<4><<<3 * 393, 256, 0, stream>>>(gb, wfc2, fc2_b, x1b + (size_t)r0 * 384,
                                            out + (size_t)r0 * 384, nr, 384, 1536, 3);
  }
}